// Round 3
// baseline (436.344 us; speedup 1.0000x reference)
//
#include <hip/hip_runtime.h>
#include <math.h>

#define NV 32768
#define CD 128
#define NCLS 10
#define KSEL 500
#define BNEPS 1e-5f
#define NK (NCLS * NV)          // 327680 keys per batch
#define H1CUT 0x3E00            // score >= 0.125 ; bins (s>>16)-H1CUT in [0,384)
#define H1BINS 384
#define CANDCAP 2048
#define ABLKROWS 64
#define ABLKPERB (NV / ABLKROWS)  // 512 stageA blocks per batch

// ---------------------------------------------------------------------------
// Stage A: hm head over all voxels. 64 rows x 128 cols per block, 128 threads,
// 8x8 per-thread micro-tile. feats in LDS row-major float4 with XOR swizzle
// m(r) = ((r>>3)&7) | ((r&3)<<3)  (write: full-width per row; read: 4 distinct
// addresses per wave land on 4 distinct bank quads -> conflict-free).
// Epilogue: BN+ReLU in regs, GEMM2 via wave shuffle reduction (cols are lanes
// tid&15), sigmoid, score-bit store, per-block hist1 partial (no atomics on
// global), plus a hist2-zero chunk for stageB's fallback path.
// ---------------------------------------------------------------------------
__global__ __launch_bounds__(128, 2) void stageA_kernel(
    const float* __restrict__ feats,
    const float* __restrict__ W1,
    const float* __restrict__ b1,
    const float* __restrict__ bng,
    const float* __restrict__ bnb,
    const float* __restrict__ bnm,
    const float* __restrict__ bnv,
    const float* __restrict__ W2hm,
    const float* __restrict__ b2hm,
    unsigned int* __restrict__ scoreb,
    unsigned int* __restrict__ hist1p,
    unsigned int* __restrict__ hist2)
{
    __shared__ __align__(16) float4 fsmv[ABLKROWS * 32];   // 32 KB
    __shared__ float w2t[NCLS * 132];                       // transposed W2hm
    __shared__ float b2s[16];
    __shared__ unsigned int lhist[H1BINS];

    const int tid = threadIdx.x;
    const int gbase = blockIdx.x * ABLKROWS;

    // zero this block's hist2 chunk (for stageB fallback): 2048 blocks x 128 w
    hist2[blockIdx.x * 128 + tid] = 0u;

    for (int i = tid; i < H1BINS; i += 128) lhist[i] = 0u;
    for (int i = tid; i < CD * NCLS; i += 128) {
        const int o = i % NCLS;
        const int c = i / NCLS;
        w2t[o * 132 + c] = W2hm[i];
    }
    if (tid < NCLS) b2s[tid] = b2hm[tid];

    // stage feats tile (swizzled)
    for (int t = tid; t < ABLKROWS * 32; t += 128) {
        const int r = t >> 5;
        const int g = t & 31;
        const float4 v = *(const float4*)(feats + (((size_t)(gbase + r)) << 7) + (g << 2));
        const int mf = ((r >> 3) & 7) | ((r & 3) << 3);
        fsmv[r * 32 + (g ^ mf)] = v;
    }
    __syncthreads();

    const int g  = tid & 15;     // col group: cols 8g..8g+7 (lane bits 0-3)
    const int rq = tid >> 4;     // row group 0..7 : rows 8rq..8rq+7
    const int c0 = g << 3;
    const int r0 = rq << 3;

    float acc[8][8];
    #pragma unroll
    for (int i = 0; i < 8; ++i)
        #pragma unroll
        for (int j = 0; j < 8; ++j) acc[i][j] = 0.f;

    #pragma unroll 2
    for (int kc = 0; kc < 32; ++kc) {
        float4 fr[8];
        #pragma unroll
        for (int i = 0; i < 8; ++i)
            fr[i] = fsmv[(r0 + i) * 32 + (kc ^ (rq | ((i & 3) << 3)))];
        const float* frp = (const float*)&fr[0];
        #pragma unroll
        for (int kk = 0; kk < 4; ++kk) {
            const int k = (kc << 2) + kk;
            const float4 wa = *(const float4*)(W1 + (k << 7) + c0);
            const float4 wb = *(const float4*)(W1 + (k << 7) + c0 + 4);
            const float w[8] = {wa.x, wa.y, wa.z, wa.w, wb.x, wb.y, wb.z, wb.w};
            #pragma unroll
            for (int ri = 0; ri < 8; ++ri) {
                const float f = frp[ri * 4 + kk];
                #pragma unroll
                for (int ci = 0; ci < 8; ++ci)
                    acc[ri][ci] = fmaf(f, w[ci], acc[ri][ci]);
            }
        }
    }

    // BN (eval) + ReLU — identical formulas/order to rounds 1-2
    #pragma unroll
    for (int ci = 0; ci < 8; ++ci) {
        const int c = c0 + ci;
        const float inv = bng[c] / sqrtf(bnv[c] + BNEPS);
        const float mu = bnm[c];
        const float be = bnb[c];
        const float bb = b1[c];
        #pragma unroll
        for (int ri = 0; ri < 8; ++ri) {
            const float h = (acc[ri][ci] + bb - mu) * inv + be;
            acc[ri][ci] = fmaxf(h, 0.f);
        }
    }

    // GEMM2 via shuffle: lanes g=0..15 hold col slices of the same 8 rows.
    const int b = gbase >> 15;                 // NV = 2^15
    const int vb = (gbase & (NV - 1)) + r0;
    unsigned int* sb = scoreb + (size_t)b * NK;
    #pragma unroll
    for (int o = 0; o < NCLS; ++o) {
        const float4 w4a = *(const float4*)&w2t[o * 132 + c0];
        const float4 w4b = *(const float4*)&w2t[o * 132 + c0 + 4];
        const float w8[8] = {w4a.x, w4a.y, w4a.z, w4a.w, w4b.x, w4b.y, w4b.z, w4b.w};
        float p[8];
        #pragma unroll
        for (int ri = 0; ri < 8; ++ri) {
            float t = 0.f;
            #pragma unroll
            for (int ci = 0; ci < 8; ++ci) t = fmaf(acc[ri][ci], w8[ci], t);
            p[ri] = t;
        }
        #pragma unroll
        for (int m = 1; m <= 8; m <<= 1) {
            #pragma unroll
            for (int ri = 0; ri < 8; ++ri) p[ri] += __shfl_xor(p[ri], m, 64);
        }
        if (g == o) {
            #pragma unroll
            for (int ri = 0; ri < 8; ++ri) {
                const float x = p[ri] + b2s[o];
                const float s = 1.f / (1.f + expf(-x));
                const unsigned int u = __float_as_uint(s);
                sb[o * NV + vb + ri] = u;
                int rel = (int)(u >> 16) - H1CUT;
                if (rel >= 0) {
                    rel = min(rel, H1BINS - 1);
                    atomicAdd(&lhist[rel], 1u);
                }
            }
        }
    }
    __syncthreads();
    for (int i = tid; i < H1BINS; i += 128)
        hist1p[(size_t)blockIdx.x * H1BINS + i] = lhist[i];
}

// ---------------------------------------------------------------------------
// Stage B: one block per batch. Sum hist1 partials -> t1 scan -> collect all
// keys with (s>>16) >= t1 (expected << 2048; exact hist2 fallback otherwise)
// -> bitonic sort desc -> emit top-500. Key = (s<<32)|~flat (jax tie order).
// ---------------------------------------------------------------------------
__global__ __launch_bounds__(1024) void stageB_kernel(
    const unsigned int* __restrict__ scoreb,
    const unsigned int* __restrict__ hist1p,
    unsigned int* __restrict__ hist2,
    float* __restrict__ sel_score,
    int* __restrict__ sel_cls,
    int* __restrict__ sel_vox)
{
    __shared__ unsigned int histS[H1BINS];
    __shared__ unsigned int csum[1024];
    __shared__ unsigned long long cand[CANDCAP];
    __shared__ int s_cnt;
    __shared__ unsigned int s_t1, s_g1, s_T;

    const int b = blockIdx.x;
    const int tid = threadIdx.x;
    const unsigned int* sb = scoreb + (size_t)b * NK;

    // phase 1: sum this batch's 512 partial hists
    if (tid < H1BINS) {
        unsigned int sum = 0;
        const unsigned int* hp = hist1p + (size_t)b * ABLKPERB * H1BINS + tid;
        #pragma unroll 8
        for (int j = 0; j < ABLKPERB; ++j) sum += hp[(size_t)j * H1BINS];
        histS[tid] = sum;
    }
    __syncthreads();
    if (tid == 0) {
        int above = 0;
        int c = H1BINS - 1;
        for (; c > 0; --c) {
            if (above + (int)histS[c] >= KSEL) break;
            above += (int)histS[c];
        }
        s_t1 = (unsigned int)(c + H1CUT);
        s_g1 = (unsigned int)above;   // count of keys with (s>>16) > t1
        s_cnt = 0;
    }
    __syncthreads();
    const unsigned int t1 = s_t1;

    // phase 2: single-scan candidate collection
    for (int i = tid; i < NK; i += 1024) {
        const unsigned int s = sb[i];
        if ((s >> 16) >= t1) {
            const int p = atomicAdd(&s_cnt, 1);
            if (p < CANDCAP)
                cand[p] = ((unsigned long long)s << 32) |
                          (unsigned long long)(0xFFFFFFFFu - (unsigned int)i);
        }
    }
    __syncthreads();
    int cnt = s_cnt;

    if (cnt > CANDCAP) {
        // exact fallback: refine inside bin t1 via 16-bit hist2
        for (int i = tid; i < NK; i += 1024) {
            const unsigned int s = sb[i];
            if ((s >> 16) == t1) atomicAdd(&hist2[(size_t)b * 65536 + (s & 0xFFFFu)], 1u);
        }
        __threadfence();
        __syncthreads();
        {
            const uint4* h4 = (const uint4*)(hist2 + (size_t)b * 65536 + tid * 64);
            unsigned int sum = 0;
            #pragma unroll
            for (int i = 0; i < 16; ++i) { const uint4 v = h4[i]; sum += v.x + v.y + v.z + v.w; }
            csum[tid] = sum;
        }
        __syncthreads();
        if (tid == 0) {
            const int need = KSEL - (int)s_g1;
            int above = 0;
            int c = 1023;
            for (; c > 0; --c) {
                if (above + (int)csum[c] >= need) break;
                above += (int)csum[c];
            }
            const unsigned int* h2 = hist2 + (size_t)b * 65536 + c * 64;
            const int need2 = need - above;
            int above2 = 0;
            int j = 63;
            for (; j > 0; --j) {
                if (above2 + (int)h2[j] >= need2) break;
                above2 += (int)h2[j];
            }
            s_T = (t1 << 16) | (unsigned int)(c * 64 + j);
            s_cnt = 0;
        }
        __syncthreads();
        const unsigned int T = s_T;
        for (int i = tid; i < NK; i += 1024) {
            const unsigned int s = sb[i];
            if (s >= T) {
                const int p = atomicAdd(&s_cnt, 1);
                if (p < CANDCAP)
                    cand[p] = ((unsigned long long)s << 32) |
                              (unsigned long long)(0xFFFFFFFFu - (unsigned int)i);
            }
        }
        __syncthreads();
        cnt = min(s_cnt, CANDCAP);
    }

    for (int i = tid; i < CANDCAP; i += 1024) if (i >= cnt) cand[i] = 0ull;
    __syncthreads();

    // bitonic sort, descending
    for (int size = 2; size <= CANDCAP; size <<= 1) {
        for (int stride = size >> 1; stride > 0; stride >>= 1) {
            #pragma unroll
            for (int half = 0; half < 2; ++half) {
                const int j = tid + (half << 10);
                const int p = j ^ stride;
                if (p > j) {
                    const unsigned long long a = cand[j];
                    const unsigned long long bb = cand[p];
                    const bool descRegion = ((j & size) == 0);
                    if ((a < bb) == descRegion) { cand[j] = bb; cand[p] = a; }
                }
            }
            __syncthreads();
        }
    }

    if (tid < KSEL) {
        const unsigned long long kk = cand[tid];
        const unsigned int s32 = (unsigned int)(kk >> 32);
        const unsigned int fl = 0xFFFFFFFFu - (unsigned int)(kk & 0xFFFFFFFFull);
        const int idx = b * KSEL + tid;
        sel_score[idx] = __uint_as_float(s32);
        sel_cls[idx] = (int)(fl >> 15);
        sel_vox[idx] = (int)(fl & (NV - 1));
    }
}

// ---------------------------------------------------------------------------
// Stage CD: heads 1..5 + decode + all outputs, 8 selections per block.
// ---------------------------------------------------------------------------
__global__ __launch_bounds__(128) void stageCD_kernel(
    const float* __restrict__ feats,
    const int* __restrict__ voxel_xy,
    const float* __restrict__ sel_score,
    const int* __restrict__ sel_cls,
    const int* __restrict__ sel_vox,
    const float* __restrict__ W1,
    const float* __restrict__ b1,
    const float* __restrict__ bng,
    const float* __restrict__ bnb,
    const float* __restrict__ bnm,
    const float* __restrict__ bnv,
    const float* __restrict__ W2c, const float* __restrict__ b2c,
    const float* __restrict__ W2z, const float* __restrict__ b2z,
    const float* __restrict__ W2d, const float* __restrict__ b2d,
    const float* __restrict__ W2r, const float* __restrict__ b2r,
    const float* __restrict__ W2v, const float* __restrict__ b2v,
    float* __restrict__ out,
    int total)
{
    __shared__ float fs[8][128];
    __shared__ float as_[8][128];
    __shared__ float decs[8][10];
    __shared__ int vsel[8];
    const int tid = threadIdx.x;
    const int s0 = blockIdx.x * 8;

    if (tid < 8) {
        const int s = s0 + tid;
        vsel[tid] = (s / KSEL) * NV + sel_vox[s];
    }
    __syncthreads();
    for (int t = tid; t < 8 * 128; t += 128) {
        const int j = t >> 7;
        const int c = t & 127;
        fs[j][c] = feats[((size_t)vsel[j] << 7) + c];
    }
    __syncthreads();

    const int c = tid;
    for (int head = 1; head <= 5; ++head) {
        float acc[8];
        #pragma unroll
        for (int j = 0; j < 8; ++j) acc[j] = 0.f;
        const float* Wh = W1 + head * (CD * CD);
        #pragma unroll 4
        for (int k = 0; k < 128; ++k) {
            const float w = Wh[(k << 7) + c];
            #pragma unroll
            for (int j = 0; j < 8; ++j) acc[j] = fmaf(fs[j][k], w, acc[j]);
        }
        const int hc = head * CD + c;
        const float inv = bng[hc] / sqrtf(bnv[hc] + BNEPS);
        const float mu = bnm[hc], be = bnb[hc], bb = b1[hc];
        #pragma unroll
        for (int j = 0; j < 8; ++j) {
            const float h = (acc[j] + bb - mu) * inv + be;
            as_[j][c] = fmaxf(h, 0.f);
        }
        __syncthreads();

        const float* w2; const float* bb2; int oc, off; bool ex = false;
        if (head == 1)      { w2 = W2c; bb2 = b2c; oc = 2; off = 0; }
        else if (head == 2) { w2 = W2z; bb2 = b2z; oc = 1; off = 2; }
        else if (head == 3) { w2 = W2d; bb2 = b2d; oc = 3; off = 3; ex = true; }
        else if (head == 4) { w2 = W2r; bb2 = b2r; oc = 2; off = 6; }
        else                { w2 = W2v; bb2 = b2v; oc = 2; off = 8; }

        for (int t = tid; t < 8 * oc; t += 128) {
            const int j = t / oc;
            const int o = t % oc;
            float a = 0.f;
            for (int cc = 0; cc < 128; ++cc) a = fmaf(as_[j][cc], w2[cc * oc + o], a);
            a += bb2[o];
            if (ex) a = expf(a);
            decs[j][off + o] = a;
        }
        __syncthreads();   // decs ready / as_ free for next head
    }

    if (tid < 8) {
        const int s = s0 + tid;
        const int b = s / KSEL;
        const float score = sel_score[s];
        const int cls = sel_cls[s];
        const int v = sel_vox[s];
        const int n = b * NV + v;
        const float xi = (float)voxel_xy[2 * n];
        const float yi = (float)voxel_xy[2 * n + 1];
        const float cx = decs[tid][0], cy = decs[tid][1], cz = decs[tid][2];
        const float d0 = decs[tid][3], d1 = decs[tid][4], d2 = decs[tid][5];
        const float rc = decs[tid][6], rs = decs[tid][7];
        const float ve0 = decs[tid][8], ve1 = decs[tid][9];
        const float SV = 0.075f * 8.0f;
        const float xs = (xi + cx) * SV + (-54.0f);
        const float ys = (yi + cy) * SV + (-54.0f);
        const float ang = atan2f(rs, rc);
        const bool mk = (xs >= -61.2f) && (ys >= -61.2f) && (cz >= -10.0f) &&
                        (xs <= 61.2f) && (ys <= 61.2f) && (cz <= 10.0f) &&
                        (score > 0.1f);
        const float m = mk ? 1.f : 0.f;
        float* bx = out + (size_t)s * 10;
        bx[0] = xs * m; bx[1] = ys * m; bx[2] = cz * m;
        bx[3] = d0 * m; bx[4] = d1 * m; bx[5] = d2 * m;
        bx[6] = ang * m; bx[7] = ve0 * m; bx[8] = ve1 * m; bx[9] = score * m;
        out[(size_t)total * 10 + s] = mk ? (float)(cls + 1) : 0.f;
        out[(size_t)total * 11 + s] = (float)n;
        out[(size_t)total * 12 + s] = m;
    }
}

extern "C" void kernel_launch(void* const* d_in, const int* in_sizes, int n_in,
                              void* d_out, int out_size, void* d_ws, size_t ws_size,
                              hipStream_t stream) {
    const float* feats   = (const float*)d_in[0];
    const int*   voxelxy = (const int*)d_in[1];
    const float* W1   = (const float*)d_in[2];
    const float* b1   = (const float*)d_in[3];
    const float* bng  = (const float*)d_in[4];
    const float* bnb  = (const float*)d_in[5];
    const float* bnm  = (const float*)d_in[6];
    const float* bnv  = (const float*)d_in[7];
    const float* W2hm = (const float*)d_in[8];
    const float* b2hm = (const float*)d_in[9];
    const float* W2c  = (const float*)d_in[10];
    const float* b2c  = (const float*)d_in[11];
    const float* W2z  = (const float*)d_in[12];
    const float* b2z  = (const float*)d_in[13];
    const float* W2d  = (const float*)d_in[14];
    const float* b2d  = (const float*)d_in[15];
    const float* W2r  = (const float*)d_in[16];
    const float* b2r  = (const float*)d_in[17];
    const float* W2v  = (const float*)d_in[18];
    const float* b2v  = (const float*)d_in[19];

    const int B = in_sizes[0] / (NV * CD);
    const int N = B * NV;
    const int total = B * KSEL;
    const int nblkA = N / ABLKROWS;

    // workspace layout
    char* ws = (char*)d_ws;
    unsigned int* scoreb = (unsigned int*)ws;   ws += (size_t)B * NK * 4;
    unsigned int* hist1p = (unsigned int*)ws;   ws += (size_t)nblkA * H1BINS * 4;
    unsigned int* hist2  = (unsigned int*)ws;   ws += (size_t)B * 65536 * 4;
    float* sel_score = (float*)ws;              ws += (size_t)total * 4;
    int*   sel_cls   = (int*)ws;                ws += (size_t)total * 4;
    int*   sel_vox   = (int*)ws;                ws += (size_t)total * 4;

    stageA_kernel<<<dim3(nblkA), dim3(128), 0, stream>>>(
        feats, W1, b1, bng, bnb, bnm, bnv, W2hm, b2hm, scoreb, hist1p, hist2);

    stageB_kernel<<<dim3(B), dim3(1024), 0, stream>>>(
        scoreb, hist1p, hist2, sel_score, sel_cls, sel_vox);

    stageCD_kernel<<<dim3(total / 8), dim3(128), 0, stream>>>(
        feats, voxelxy, sel_score, sel_cls, sel_vox,
        W1, b1, bng, bnb, bnm, bnv,
        W2c, b2c, W2z, b2z, W2d, b2d, W2r, b2r, W2v, b2v,
        (float*)d_out, total);
}